// Round 7
// baseline (936.190 us; speedup 1.0000x reference)
//
#include <hip/hip_runtime.h>
#include <math.h>
#include <stdint.h>

#define NR_ 16384
#define NP2_ 40000
#define NM_ 30000
#define NE_ 200000
#define EMB_ 1024
#define HID_ 256
#define OUTD_ 128

typedef __attribute__((ext_vector_type(8))) short bf16x8;
typedef __attribute__((ext_vector_type(4))) float f32x4;
typedef __attribute__((ext_vector_type(8))) unsigned short us8;

__device__ __forceinline__ unsigned short f2bf(float f) {
    uint32_t u = __builtin_bit_cast(uint32_t, f);
    u = (u + 0x7FFFu + ((u >> 16) & 1u)) >> 16;
    return (unsigned short)u;
}
__device__ __forceinline__ float bf2f(unsigned short u) {
    uint32_t v = ((uint32_t)u) << 16;
    return __builtin_bit_cast(float, v);
}

// ---------------- batched CSR build ----------------
struct Csr4 {
    const int* src[4]; const int* dst[4];
    int* offs[4]; int* cur[4]; int* csr[4];
    int n[4];
};
__global__ void k_zero4(Csr4 c) {
    int y = blockIdx.y;
    int i = blockIdx.x * 256 + threadIdx.x;
    if (i < c.n[y]) c.cur[y][i] = 0;
}
__global__ void k_deg4(Csr4 c) {
    int y = blockIdx.y;
    int i = blockIdx.x * 256 + threadIdx.x;
    if (i < NE_) atomicAdd(&c.cur[y][c.dst[y][i]], 1);
}
// two-level scan: A = per-1024-chunk block scan, B = chunk-sum scan, C = add base + init cur
__global__ void k_scanA(Csr4 c, int* __restrict__ csum) {
    int y = blockIdx.y;
    int n = c.n[y];
    int ch = blockIdx.x;
    int nch = (n + 1023) >> 10;
    if (ch >= nch) return;
    const int* deg = c.cur[y];
    int* offs = c.offs[y];
    __shared__ int ts[256];
    int base = ch << 10;
    int t = threadIdx.x;
    int v[4];
    int s = 0;
    #pragma unroll
    for (int k = 0; k < 4; ++k) {
        int i = base + t * 4 + k;
        v[k] = (i < n) ? deg[i] : 0;
        s += v[k];
    }
    ts[t] = s;
    __syncthreads();
    for (int st = 1; st < 256; st <<= 1) {
        int x = ts[t];
        int xo = (t >= st) ? ts[t - st] : 0;
        __syncthreads();
        ts[t] = x + xo;
        __syncthreads();
    }
    int run = (t > 0) ? ts[t - 1] : 0;
    #pragma unroll
    for (int k = 0; k < 4; ++k) {
        int i = base + t * 4 + k;
        if (i < n) offs[i] = run;
        run += v[k];
    }
    if (t == 255) csum[y * 40 + ch] = ts[255];
}
__global__ void k_scanB(Csr4 c, int* __restrict__ csum) {
    int y = threadIdx.x;
    if (y < 4) {
        int n = c.n[y];
        int nch = (n + 1023) >> 10;
        int acc = 0;
        for (int i = 0; i < nch; ++i) {
            int v = csum[y * 40 + i];
            csum[y * 40 + i] = acc;
            acc += v;
        }
        c.offs[y][n] = acc;
    }
}
__global__ void k_scanC(Csr4 c, const int* __restrict__ csum) {
    int y = blockIdx.y;
    int i = blockIdx.x * 256 + threadIdx.x;
    if (i < c.n[y]) {
        int v = c.offs[y][i] + csum[y * 40 + (i >> 10)];
        c.offs[y][i] = v;
        c.cur[y][i] = v;
    }
}
__global__ void k_scatter4(Csr4 c) {
    int y = blockIdx.y;
    int i = blockIdx.x * 256 + threadIdx.x;
    if (i < NE_) {
        int d = c.dst[y][i];
        int p = atomicAdd(&c.cur[y][d], 1);
        c.csr[y][p] = c.src[y][i];
    }
}

// batched weight transpose+convert: dst[n*K+k] = bf16(a[k*N+n] (+ b[k*N+n]))
struct WItem { const float* a; const float* b; unsigned short* dst; int k; int n; };
struct WBatch { WItem it[32]; };
__global__ void k_wconvT(WBatch wb) {
    WItem w = wb.it[blockIdx.y];
    int total = w.k * w.n;
    int kmask = w.k - 1;
    int shift = (w.k == 1024) ? 10 : 8;
    for (int idx = blockIdx.x * 256 + threadIdx.x; idx < total; idx += gridDim.x * 256) {
        int k = idx & kmask, n = idx >> shift;
        float v = w.a[(size_t)k * w.n + n];
        if (w.b) v += w.b[(size_t)k * w.n + n];
        w.dst[idx] = f2bf(v);
    }
}

// ---------------- bf16 MFMA GEMM: C[M, Ntiles*128] = A[M,K](lda) @ Bt[N,K]^T ----------------
// 2-phase double-buffered pipeline (T3 minimum recipe): stage tile t+1 BEFORE computing
// tile t; ONE __syncthreads per K-step (its vmcnt(0)+lgkmcnt(0) drain is the pipeline wait).
// AF32: A is f32 -> T14 async split: issue loads early, convert+ds_write after compute
// (writes target the buffer no wave reads this iteration -> no extra barrier needed).
// Operand-swapped MFMA: D = mfma(bfr, af) -> lane holds 4 consecutive C columns.
template <bool OBF, bool AF32>
__global__ __launch_bounds__(256, 2) void k_gemm(
    const void* __restrict__ Av, int lda,
    const unsigned short* __restrict__ Bt,
    void* __restrict__ Cv, int ldc, const float* __restrict__ bias,
    int M, int K)
{
    __shared__ __align__(16) unsigned short As[2][128 * 64];
    __shared__ __align__(16) unsigned short Bs[2][128 * 64];
    const int tid = threadIdx.x;
    const int lane = tid & 63;
    // ---- XCD-chunk swizzle, col-tile fastest ----
    int nwg = gridDim.x * gridDim.y;
    int o = blockIdx.y * gridDim.x + blockIdx.x;
    int q = nwg >> 3, r = nwg & 7;
    int xcd = o & 7, j = o >> 3;
    int wg = (xcd < r ? xcd * (q + 1) : r * (q + 1) + (xcd - r) * q) + j;
    const int bm = (wg / gridDim.y) * 128;
    const int bn = (wg % gridDim.y) * 128;
    const int wave = tid >> 6;
    const int wr = (wave >> 1) * 64;
    const int wc = (wave & 1) * 64;
    const int frow = lane & 15;
    const int fkc = lane >> 4;
    f32x4 acc[4][4] = {};
    float4 ra0[4], ra1[4];
    (void)ra0; (void)ra1;

#define STAGE_AB(bufi, kk0) do {                                                           \
    _Pragma("unroll")                                                                      \
    for (int i = 0; i < 4; ++i) {                                                          \
        int c = tid + i * 256, rw = c >> 3, kc = c & 7;                                    \
        int srck = (kk0) + ((kc ^ (rw & 7)) << 3);                                         \
        int ga = min(bm + rw, M - 1);                                                      \
        __builtin_amdgcn_global_load_lds(                                                  \
            (const __attribute__((address_space(1))) unsigned int*)((const unsigned short*)Av + (size_t)ga * lda + srck), \
            (__attribute__((address_space(3))) unsigned int*)(&As[bufi][c * 8]), 16, 0, 0);\
        __builtin_amdgcn_global_load_lds(                                                  \
            (const __attribute__((address_space(1))) unsigned int*)(Bt + (size_t)(bn + rw) * K + srck), \
            (__attribute__((address_space(3))) unsigned int*)(&Bs[bufi][c * 8]), 16, 0, 0);\
    } } while (0)

#define ALOAD(kk0) do {                                                                    \
    _Pragma("unroll")                                                                      \
    for (int i = 0; i < 4; ++i) {                                                          \
        int c = tid + i * 256, rw = c >> 3, kc = c & 7;                                    \
        int srck = (kk0) + ((kc ^ (rw & 7)) << 3);                                         \
        int ga = min(bm + rw, M - 1);                                                      \
        const float* Af = (const float*)Av + (size_t)ga * lda + srck;                      \
        ra0[i] = *(const float4*)Af;                                                       \
        ra1[i] = *(const float4*)(Af + 4);                                                 \
    } } while (0)

#define AWRITE(bufi) do {                                                                  \
    _Pragma("unroll")                                                                      \
    for (int i = 0; i < 4; ++i) {                                                          \
        int c = tid + i * 256;                                                             \
        us8 oo;                                                                            \
        oo[0] = f2bf(ra0[i].x); oo[1] = f2bf(ra0[i].y);                                    \
        oo[2] = f2bf(ra0[i].z); oo[3] = f2bf(ra0[i].w);                                    \
        oo[4] = f2bf(ra1[i].x); oo[5] = f2bf(ra1[i].y);                                    \
        oo[6] = f2bf(ra1[i].z); oo[7] = f2bf(ra1[i].w);                                    \
        *(us8*)(&As[bufi][c * 8]) = oo;                                                    \
    } } while (0)

#define STAGE_B(bufi, kk0) do {                                                            \
    _Pragma("unroll")                                                                      \
    for (int i = 0; i < 4; ++i) {                                                          \
        int c = tid + i * 256, rw = c >> 3, kc = c & 7;                                    \
        int srck = (kk0) + ((kc ^ (rw & 7)) << 3);                                         \
        __builtin_amdgcn_global_load_lds(                                                  \
            (const __attribute__((address_space(1))) unsigned int*)(Bt + (size_t)(bn + rw) * K + srck), \
            (__attribute__((address_space(3))) unsigned int*)(&Bs[bufi][c * 8]), 16, 0, 0);\
    } } while (0)

#define COMPUTE(bufi) do {                                                                 \
    _Pragma("unroll")                                                                      \
    for (int kk = 0; kk < 2; ++kk) {                                                       \
        bf16x8 af[4], bfr[4];                                                              \
        _Pragma("unroll")                                                                  \
        for (int m = 0; m < 4; ++m) {                                                      \
            int rw = wr + m * 16 + frow;                                                   \
            int kc = kk * 4 + fkc;                                                         \
            af[m] = *(const bf16x8*)(&As[bufi][((rw << 3) + (kc ^ (rw & 7))) * 8]);        \
        }                                                                                  \
        _Pragma("unroll")                                                                  \
        for (int n = 0; n < 4; ++n) {                                                      \
            int rw = wc + n * 16 + frow;                                                   \
            int kc = kk * 4 + fkc;                                                         \
            bfr[n] = *(const bf16x8*)(&Bs[bufi][((rw << 3) + (kc ^ (rw & 7))) * 8]);       \
        }                                                                                  \
        _Pragma("unroll")                                                                  \
        for (int m = 0; m < 4; ++m)                                                        \
            _Pragma("unroll")                                                              \
            for (int n = 0; n < 4; ++n)                                                    \
                acc[m][n] = __builtin_amdgcn_mfma_f32_16x16x32_bf16(bfr[n], af[m], acc[m][n], 0, 0, 0); \
    } } while (0)

    const int nt = K >> 6;
    if constexpr (AF32) {
        ALOAD(0);
        STAGE_B(0, 0);
        AWRITE(0);
        __syncthreads();
        for (int t = 0; t < nt; ++t) {
            int bufi = t & 1;
            if (t + 1 < nt) {
                ALOAD((t + 1) << 6);
                STAGE_B(bufi ^ 1, (t + 1) << 6);
            }
            COMPUTE(bufi);
            if (t + 1 < nt) AWRITE(bufi ^ 1);  // writes buffer nobody reads this iter
            __syncthreads();
        }
    } else {
        STAGE_AB(0, 0);
        __syncthreads();
        for (int t = 0; t < nt; ++t) {
            int bufi = t & 1;
            if (t + 1 < nt) STAGE_AB(bufi ^ 1, (t + 1) << 6);
            COMPUTE(bufi);
            __syncthreads();
        }
    }

    // D = Bt_tile · A_tile^T: X-dim (lane>>4, reg) = C col, Y-dim (lane&15) = C row
    const int ccol0 = (lane >> 4) << 2;
    #pragma unroll
    for (int m = 0; m < 4; ++m) {
        int row = bm + wr + m * 16 + frow;
        if (row < M) {
            #pragma unroll
            for (int n = 0; n < 4; ++n) {
                int col = bn + wc + n * 16 + ccol0;
                f32x4 v = acc[m][n];
                if (bias) {
                    v[0] += bias[col + 0];
                    v[1] += bias[col + 1];
                    v[2] += bias[col + 2];
                    v[3] += bias[col + 3];
                }
                if constexpr (OBF) {
                    ushort4 oo;
                    oo.x = f2bf(v[0]); oo.y = f2bf(v[1]); oo.z = f2bf(v[2]); oo.w = f2bf(v[3]);
                    *(ushort4*)((unsigned short*)Cv + (size_t)row * ldc + col) = oo;
                } else {
                    *(float4*)((float*)Cv + (size_t)row * ldc + col) = make_float4(v[0], v[1], v[2], v[3]);
                }
            }
        }
    }
#undef STAGE_AB
#undef ALOAD
#undef AWRITE
#undef STAGE_B
#undef COMPUTE
}

// ---------------- wave-per-node CSR mean-aggregate (bf16 RMW: outx += mean + bias) ----------------
__global__ __launch_bounds__(256) void k_aggw(const int* __restrict__ offs,
                                              const int* __restrict__ csr,
                                              const unsigned short* __restrict__ proj, int ldp,
                                              const float* __restrict__ bias,
                                              unsigned short* __restrict__ outx, int ldo,
                                              int ndst) {
    int node = blockIdx.x * 4 + (threadIdx.x >> 6);
    int lane = threadIdx.x & 63;
    if (node >= ndst) return;
    int beg = offs[node], end = offs[node + 1];
    float s0 = 0.f, s1 = 0.f, s2 = 0.f, s3 = 0.f;
    const unsigned short* base = proj + lane * 4;
    int e = beg;
    for (; e + 1 < end; e += 2) {
        int i0 = csr[e], i1 = csr[e + 1];
        ushort4 u0 = *(const ushort4*)(base + (size_t)i0 * ldp);
        ushort4 u1 = *(const ushort4*)(base + (size_t)i1 * ldp);
        s0 += bf2f(u0.x) + bf2f(u1.x);
        s1 += bf2f(u0.y) + bf2f(u1.y);
        s2 += bf2f(u0.z) + bf2f(u1.z);
        s3 += bf2f(u0.w) + bf2f(u1.w);
    }
    if (e < end) {
        ushort4 u = *(const ushort4*)(base + (size_t)csr[e] * ldp);
        s0 += bf2f(u.x); s1 += bf2f(u.y); s2 += bf2f(u.z); s3 += bf2f(u.w);
    }
    float inv = 1.f / fmaxf((float)(end - beg), 1.f);
    float4 b4 = ((const float4*)bias)[lane];
    size_t o = (size_t)node * ldo + lane * 4;
    ushort4 cur = *(const ushort4*)(outx + o);
    ushort4 w;
    w.x = f2bf(bf2f(cur.x) + s0 * inv + b4.x);
    w.y = f2bf(bf2f(cur.y) + s1 * inv + b4.y);
    w.z = f2bf(bf2f(cur.z) + s2 * inv + b4.z);
    w.w = f2bf(bf2f(cur.w) + s3 * inv + b4.w);
    *(ushort4*)(outx + o) = w;
}

// dual-source wave aggregate (reaction dst: p2r + m2r in one pass)
__global__ __launch_bounds__(256) void k_agg2w(const int* __restrict__ offsA,
                                               const int* __restrict__ csrA,
                                               const unsigned short* __restrict__ projA, int ldpA,
                                               const float* __restrict__ biasA,
                                               const int* __restrict__ offsB,
                                               const int* __restrict__ csrB,
                                               const unsigned short* __restrict__ projB, int ldpB,
                                               const float* __restrict__ biasB,
                                               unsigned short* __restrict__ outx, int ldo,
                                               int ndst) {
    int node = blockIdx.x * 4 + (threadIdx.x >> 6);
    int lane = threadIdx.x & 63;
    if (node >= ndst) return;
    float a0 = 0.f, a1 = 0.f, a2 = 0.f, a3 = 0.f;
    int begA = offsA[node], endA = offsA[node + 1];
    const unsigned short* baseA = projA + lane * 4;
    int e = begA;
    for (; e + 1 < endA; e += 2) {
        int i0 = csrA[e], i1 = csrA[e + 1];
        ushort4 u0 = *(const ushort4*)(baseA + (size_t)i0 * ldpA);
        ushort4 u1 = *(const ushort4*)(baseA + (size_t)i1 * ldpA);
        a0 += bf2f(u0.x) + bf2f(u1.x);
        a1 += bf2f(u0.y) + bf2f(u1.y);
        a2 += bf2f(u0.z) + bf2f(u1.z);
        a3 += bf2f(u0.w) + bf2f(u1.w);
    }
    if (e < endA) {
        ushort4 u = *(const ushort4*)(baseA + (size_t)csrA[e] * ldpA);
        a0 += bf2f(u.x); a1 += bf2f(u.y); a2 += bf2f(u.z); a3 += bf2f(u.w);
    }
    float b0 = 0.f, b1 = 0.f, b2 = 0.f, b3 = 0.f;
    int begB = offsB[node], endB = offsB[node + 1];
    const unsigned short* baseB = projB + lane * 4;
    e = begB;
    for (; e + 1 < endB; e += 2) {
        int i0 = csrB[e], i1 = csrB[e + 1];
        ushort4 u0 = *(const ushort4*)(baseB + (size_t)i0 * ldpB);
        ushort4 u1 = *(const ushort4*)(baseB + (size_t)i1 * ldpB);
        b0 += bf2f(u0.x) + bf2f(u1.x);
        b1 += bf2f(u0.y) + bf2f(u1.y);
        b2 += bf2f(u0.z) + bf2f(u1.z);
        b3 += bf2f(u0.w) + bf2f(u1.w);
    }
    if (e < endB) {
        ushort4 u = *(const ushort4*)(baseB + (size_t)csrB[e] * ldpB);
        b0 += bf2f(u.x); b1 += bf2f(u.y); b2 += bf2f(u.z); b3 += bf2f(u.w);
    }
    float invA = 1.f / fmaxf((float)(endA - begA), 1.f);
    float invB = 1.f / fmaxf((float)(endB - begB), 1.f);
    float4 bA = ((const float4*)biasA)[lane];
    float4 bB = ((const float4*)biasB)[lane];
    size_t o = (size_t)node * ldo + lane * 4;
    ushort4 cur = *(const ushort4*)(outx + o);
    ushort4 w;
    w.x = f2bf(bf2f(cur.x) + a0 * invA + bA.x + b0 * invB + bB.x);
    w.y = f2bf(bf2f(cur.y) + a1 * invA + bA.y + b1 * invB + bB.y);
    w.z = f2bf(bf2f(cur.z) + a2 * invA + bA.z + b2 * invB + bB.z);
    w.w = f2bf(bf2f(cur.w) + a3 * invA + bA.w + b3 * invB + bB.w);
    *(ushort4*)(outx + o) = w;
}

// ---------------- cosine: one wave per row ----------------
__global__ __launch_bounds__(256) void k_cos(const float* __restrict__ ro,
                                             const float* __restrict__ pr,
                                             const int* __restrict__ types,
                                             float* __restrict__ out, int nr) {
    int row = blockIdx.x * 4 + (threadIdx.x >> 6);
    int lane = threadIdx.x & 63;
    if (row >= nr) return;
    int t = types[row];
    float2 r = ((const float2*)(ro + (size_t)row * OUTD_))[lane];
    float2 nn = ((const float2*)(pr + (size_t)row * 384 + t * OUTD_))[lane];
    float num = r.x * nn.x + r.y * nn.y;
    float d1 = r.x * r.x + r.y * r.y;
    float d2 = nn.x * nn.x + nn.y * nn.y;
    #pragma unroll
    for (int s = 1; s < 64; s <<= 1) {
        num += __shfl_xor(num, s);
        d1 += __shfl_xor(d1, s);
        d2 += __shfl_xor(d2, s);
    }
    if (lane == 0) out[row] = (num / fmaxf(sqrtf(d1) * sqrtf(d2), 1e-8f) + 1.f) * 0.5f;
}

extern "C" void kernel_launch(void* const* d_in, const int* in_sizes, int n_in,
                              void* d_out, int out_size, void* d_ws, size_t ws_size,
                              hipStream_t stream) {
    const float* x_r0 = (const float*)d_in[0];
    const float* x_p0 = (const float*)d_in[1];
    const float* x_m0 = (const float*)d_in[2];
    const int* e_src[4] = {(const int*)d_in[3], (const int*)d_in[5], (const int*)d_in[7], (const int*)d_in[9]};
    const int* e_dst[4] = {(const int*)d_in[4], (const int*)d_in[6], (const int*)d_in[8], (const int*)d_in[10]};
    const float* notes = (const float*)d_in[11];
    const int* types = (const int*)d_in[12];
    const float* Wl0 = (const float*)d_in[13];
    const float* Wr0 = (const float*)d_in[14];
    const float* bl0 = (const float*)d_in[15];
    const float* WlL = (const float*)d_in[16];
    const float* WrL = (const float*)d_in[17];
    const float* blL = (const float*)d_in[18];
    const float* Wre = (const float*)d_in[19];
    const float* bre = (const float*)d_in[20];
    const float* Wn  = (const float*)d_in[21];
    const float* bn  = (const float*)d_in[22];
    float* out = (float*)d_out;

    // ---- workspace carve ----
    uintptr_t base = (uintptr_t)d_ws;
    auto alloc = [&](size_t bytes) -> void* {
        uintptr_t p = (base + 255) & ~(uintptr_t)255;
        base = p + bytes;
        return (void*)p;
    };
    unsigned short* Rb[2] = {(unsigned short*)alloc((size_t)NR_ * 768 * 2),
                             (unsigned short*)alloc((size_t)NR_ * 768 * 2)};
    unsigned short* Pb[2] = {(unsigned short*)alloc((size_t)NP2_ * 512 * 2),
                             (unsigned short*)alloc((size_t)NP2_ * 512 * 2)};
    unsigned short* Mb[2] = {(unsigned short*)alloc((size_t)NM_ * 512 * 2),
                             (unsigned short*)alloc((size_t)NM_ * 512 * 2)};
    float* ro = (float*)alloc((size_t)NR_ * OUTD_ * 4);
    float* pr = (float*)alloc((size_t)NR_ * 384 * 4);
    unsigned short* wbf = (unsigned short*)alloc((size_t)4000000 * 2);
    int* csum = (int*)alloc(160 * 4);
    int nd[4] = {NR_, NR_, NP2_, NM_};
    Csr4 cs{};
    for (int t = 0; t < 4; ++t) {
        cs.src[t] = e_src[t]; cs.dst[t] = e_dst[t]; cs.n[t] = nd[t];
        cs.offs[t] = (int*)alloc(((size_t)nd[t] + 1) * 4);
        cs.cur[t]  = (int*)alloc((size_t)nd[t] * 4);
        cs.csr[t]  = (int*)alloc((size_t)NE_ * 4);
    }

    // ---- weight transpose+convert: concatenated B blocks, bf16 [N][K] ----
    unsigned short *BR[4], *BP[4], *BM[4], *Bre, *Bn;
    {
        WBatch wb{};
        int cnt = 0;
        size_t woff = 0;
        auto add = [&](const float* a, const float* bb, int K, int N) -> unsigned short* {
            unsigned short* dst = wbf + woff;
            woff += (size_t)K * N;
            wb.it[cnt] = WItem{a, bb, dst, K, N};
            ++cnt;
            return dst;
        };
        const size_t w0 = (size_t)EMB_ * HID_;
        const size_t wl = (size_t)HID_ * HID_;
        for (int l = 0; l < 4; ++l) {
            int K = (l == 0) ? EMB_ : HID_;
            const float* Wr_ = (l == 0) ? Wr0 : WrL + (size_t)(l - 1) * 4 * wl;
            const float* Wl_ = (l == 0) ? Wl0 : WlL + (size_t)(l - 1) * 4 * wl;
            size_t ws_ = (l == 0) ? w0 : wl;
            BR[l] = add(Wr_ + 0 * ws_, Wr_ + 1 * ws_, K, HID_);  // WrC
            add(Wl_ + 2 * ws_, nullptr, K, HID_);                 // Wl2 (r2p proj)
            add(Wl_ + 3 * ws_, nullptr, K, HID_);                 // Wl3 (r2m proj)
            BP[l] = add(Wr_ + 2 * ws_, nullptr, K, HID_);         // Wr2
            add(Wl_ + 0 * ws_, nullptr, K, HID_);                 // Wl0 (p2r proj)
            BM[l] = add(Wr_ + 3 * ws_, nullptr, K, HID_);         // Wr3
            add(Wl_ + 1 * ws_, nullptr, K, HID_);                 // Wl1 (m2r proj)
        }
        Bre = add(Wre, nullptr, HID_, OUTD_);
        Bn = add(Wn + 0 * (size_t)EMB_ * OUTD_, nullptr, EMB_, OUTD_);
        add(Wn + 1 * (size_t)EMB_ * OUTD_, nullptr, EMB_, OUTD_);
        add(Wn + 2 * (size_t)EMB_ * OUTD_, nullptr, EMB_, OUTD_);
        k_wconvT<<<dim3(128, cnt), 256, 0, stream>>>(wb);
    }

    // ---- CSR build (batched over the 4 edge types) ----
    k_zero4<<<dim3((NP2_ + 255) / 256, 4), 256, 0, stream>>>(cs);
    k_deg4<<<dim3((NE_ + 255) / 256, 4), 256, 0, stream>>>(cs);
    k_scanA<<<dim3(40, 4), 256, 0, stream>>>(cs, csum);
    k_scanB<<<1, 64, 0, stream>>>(cs, csum);
    k_scanC<<<dim3((NP2_ + 255) / 256, 4), 256, 0, stream>>>(cs, csum);
    k_scatter4<<<dim3((NE_ + 255) / 256, 4), 256, 0, stream>>>(cs);

    auto gemm_bf = [&](const unsigned short* A, int lda, const unsigned short* Bt,
                       unsigned short* C, int ldc, int M, int N, int K) {
        k_gemm<true, false><<<dim3((M + 127) / 128, N / 128), 256, 0, stream>>>(
            A, lda, Bt, C, ldc, nullptr, M, K);
    };
    auto gemm_f32a_bf = [&](const float* A, int lda, const unsigned short* Bt,
                            unsigned short* C, int ldc, int M, int N, int K) {
        k_gemm<true, true><<<dim3((M + 127) / 128, N / 128), 256, 0, stream>>>(
            A, lda, Bt, C, ldc, nullptr, M, K);
    };

    for (int l = 0; l < 4; ++l) {
        int K = (l == 0) ? EMB_ : HID_;
        unsigned short* R = Rb[l & 1];
        unsigned short* P = Pb[l & 1];
        unsigned short* M = Mb[l & 1];
        const float* bl_ = (l == 0) ? bl0 : blL + (size_t)(l - 1) * 4 * HID_;

        if (l == 0) {
            gemm_f32a_bf(x_r0, EMB_, BR[0], R, 768, NR_, 768, EMB_);
            gemm_f32a_bf(x_p0, EMB_, BP[0], P, 512, NP2_, 512, EMB_);
            gemm_f32a_bf(x_m0, EMB_, BM[0], M, 512, NM_, 512, EMB_);
        } else {
            gemm_bf(Rb[(l - 1) & 1], 768, BR[l], R, 768, NR_, 768, K);
            gemm_bf(Pb[(l - 1) & 1], 512, BP[l], P, 512, NP2_, 512, K);
            gemm_bf(Mb[(l - 1) & 1], 512, BM[l], M, 512, NM_, 512, K);
        }

        // reaction <- mean(projP) + mean(projM); protein <- mean(projR); molecule <- mean(projR2)
        k_agg2w<<<(NR_ + 3) / 4, 256, 0, stream>>>(cs.offs[0], cs.csr[0], P + 256, 512, bl_ + 0 * HID_,
                                                   cs.offs[1], cs.csr[1], M + 256, 512, bl_ + 1 * HID_,
                                                   R, 768, NR_);
        k_aggw<<<(NP2_ + 3) / 4, 256, 0, stream>>>(cs.offs[2], cs.csr[2], R + 256, 768, bl_ + 2 * HID_, P, 512, NP2_);
        k_aggw<<<(NM_ + 3) / 4, 256, 0, stream>>>(cs.offs[3], cs.csr[3], R + 512, 768, bl_ + 3 * HID_, M, 512, NM_);
    }

    // ---- final: reaction proj (f32 out) + 3 node projs (f32 out, concatenated) + cosine ----
    k_gemm<false, false><<<dim3((NR_ + 127) / 128, 1), 256, 0, stream>>>(
        Rb[1], 768, Bre, ro, OUTD_, bre, NR_, HID_);
    k_gemm<false, true><<<dim3((NR_ + 127) / 128, 3), 256, 0, stream>>>(
        notes, EMB_, Bn, pr, 384, bn, NR_, EMB_);
    k_cos<<<NR_ / 4, 256, 0, stream>>>(ro, pr, types, out, NR_);
}

// Round 8
// 805.501 us; speedup vs baseline: 1.1622x; 1.1622x over previous
//
#include <hip/hip_runtime.h>
#include <math.h>
#include <stdint.h>

#define NR_ 16384
#define NP2_ 40000
#define NM_ 30000
#define NE_ 200000
#define EMB_ 1024
#define HID_ 256
#define OUTD_ 128

typedef __attribute__((ext_vector_type(8))) short bf16x8;
typedef __attribute__((ext_vector_type(4))) float f32x4;
typedef __attribute__((ext_vector_type(8))) unsigned short us8;

__device__ __forceinline__ unsigned short f2bf(float f) {
    uint32_t u = __builtin_bit_cast(uint32_t, f);
    u = (u + 0x7FFFu + ((u >> 16) & 1u)) >> 16;
    return (unsigned short)u;
}
__device__ __forceinline__ float bf2f(unsigned short u) {
    uint32_t v = ((uint32_t)u) << 16;
    return __builtin_bit_cast(float, v);
}

// ---------------- batched CSR build ----------------
struct Csr4 {
    const int* src[4]; const int* dst[4];
    int* offs[4]; int* cur[4]; int* csr[4];
    int n[4];
};
__global__ void k_zero4(Csr4 c) {
    int y = blockIdx.y;
    int i = blockIdx.x * 256 + threadIdx.x;
    if (i < c.n[y]) c.cur[y][i] = 0;
}
__global__ void k_deg4(Csr4 c) {
    int y = blockIdx.y;
    int i = blockIdx.x * 256 + threadIdx.x;
    if (i < NE_) atomicAdd(&c.cur[y][c.dst[y][i]], 1);
}
__global__ void k_scanA(Csr4 c, int* __restrict__ csum) {
    int y = blockIdx.y;
    int n = c.n[y];
    int ch = blockIdx.x;
    int nch = (n + 1023) >> 10;
    if (ch >= nch) return;
    const int* deg = c.cur[y];
    int* offs = c.offs[y];
    __shared__ int ts[256];
    int base = ch << 10;
    int t = threadIdx.x;
    int v[4];
    int s = 0;
    #pragma unroll
    for (int k = 0; k < 4; ++k) {
        int i = base + t * 4 + k;
        v[k] = (i < n) ? deg[i] : 0;
        s += v[k];
    }
    ts[t] = s;
    __syncthreads();
    for (int st = 1; st < 256; st <<= 1) {
        int x = ts[t];
        int xo = (t >= st) ? ts[t - st] : 0;
        __syncthreads();
        ts[t] = x + xo;
        __syncthreads();
    }
    int run = (t > 0) ? ts[t - 1] : 0;
    #pragma unroll
    for (int k = 0; k < 4; ++k) {
        int i = base + t * 4 + k;
        if (i < n) offs[i] = run;
        run += v[k];
    }
    if (t == 255) csum[y * 40 + ch] = ts[255];
}
__global__ void k_scanB(Csr4 c, int* __restrict__ csum) {
    int y = threadIdx.x;
    if (y < 4) {
        int n = c.n[y];
        int nch = (n + 1023) >> 10;
        int acc = 0;
        for (int i = 0; i < nch; ++i) {
            int v = csum[y * 40 + i];
            csum[y * 40 + i] = acc;
            acc += v;
        }
        c.offs[y][n] = acc;
    }
}
__global__ void k_scanC(Csr4 c, const int* __restrict__ csum) {
    int y = blockIdx.y;
    int i = blockIdx.x * 256 + threadIdx.x;
    if (i < c.n[y]) {
        int v = c.offs[y][i] + csum[y * 40 + (i >> 10)];
        c.offs[y][i] = v;
        c.cur[y][i] = v;
    }
}
__global__ void k_scatter4(Csr4 c) {
    int y = blockIdx.y;
    int i = blockIdx.x * 256 + threadIdx.x;
    if (i < NE_) {
        int d = c.dst[y][i];
        int p = atomicAdd(&c.cur[y][d], 1);
        c.csr[y][p] = c.src[y][i];
    }
}

// batched weight transpose+convert: dst[n*K+k] = bf16(a[k*N+n] (+ b[k*N+n]))
struct WItem { const float* a; const float* b; unsigned short* dst; int k; int n; };
struct WBatch { WItem it[32]; };
__global__ void k_wconvT(WBatch wb) {
    WItem w = wb.it[blockIdx.y];
    int total = w.k * w.n;
    int kmask = w.k - 1;
    int shift = (w.k == 1024) ? 10 : 8;
    for (int idx = blockIdx.x * 256 + threadIdx.x; idx < total; idx += gridDim.x * 256) {
        int k = idx & kmask, n = idx >> shift;
        float v = w.a[(size_t)k * w.n + n];
        if (w.b) v += w.b[(size_t)k * w.n + n];
        w.dst[idx] = f2bf(v);
    }
}

// ---------------- batched bf16 MFMA GEMM ----------------
// Round-6-proven core (single 32KB LDS buffer, 3 blocks/CU), extended to a
// segment table so one dispatch runs up to 3 GEMMs (kills tails + launches).
// Flat block id -> bijective XCD-chunk swizzle -> segment -> (bm, bn),
// col-tile fastest within a segment (A-panel L2 reuse on one XCD).
// AF32: A is f32, reg-staged + converted to bf16 during LDS write.
// Operand-swapped MFMA: D = mfma(bfr, af) -> lane holds 4 consecutive C cols.
struct GSeg {
    const void* A; const unsigned short* Bt; void* C; const float* bias;
    int lda, ldc, M, K, ntn, blk0;
};
struct GBatch { GSeg s[3]; int b1, b2, tot; };

template <bool OBF, bool AF32>
__global__ __launch_bounds__(256, 3) void k_gemmb(GBatch gb) {
    __shared__ __align__(16) unsigned short As[128 * 64];
    __shared__ __align__(16) unsigned short Bs[128 * 64];
    const int tid = threadIdx.x;
    const int lane = tid & 63;
    // ---- bijective XCD-chunk swizzle over the merged grid ----
    int nwg = gb.tot;
    int o = blockIdx.x;
    int q = nwg >> 3, r = nwg & 7;
    int xcd = o & 7, j = o >> 3;
    int wg = (xcd < r ? xcd * (q + 1) : r * (q + 1) + (xcd - r) * q) + j;
    const int si = (wg >= gb.b1) + (wg >= gb.b2);
    const GSeg sg = gb.s[si];
    const int local = wg - sg.blk0;
    const int bm = (local / sg.ntn) * 128;
    const int bn = (local % sg.ntn) * 128;
    const int lda = sg.lda, ldc = sg.ldc, M = sg.M, K = sg.K;
    const unsigned short* __restrict__ Bt = sg.Bt;
    const float* __restrict__ bias = sg.bias;

    const int wave = tid >> 6;
    const int wr = (wave >> 1) * 64;
    const int wc = (wave & 1) * 64;
    const int frow = lane & 15;
    const int fkc = lane >> 4;
    f32x4 acc[4][4] = {};

    for (int k0 = 0; k0 < K; k0 += 64) {
        #pragma unroll
        for (int i = 0; i < 4; ++i) {
            int c = tid + i * 256;               // chunk 0..1023 (16B each)
            int row = c >> 3, kc = c & 7;
            int srck = k0 + ((kc ^ (row & 7)) << 3);  // pre-swizzled global source
            int ga = min(bm + row, M - 1);
            if constexpr (AF32) {
                const float* Af = (const float*)sg.A + (size_t)ga * lda + srck;
                float4 a0 = *(const float4*)Af;
                float4 a1 = *(const float4*)(Af + 4);
                us8 oo;
                oo[0] = f2bf(a0.x); oo[1] = f2bf(a0.y); oo[2] = f2bf(a0.z); oo[3] = f2bf(a0.w);
                oo[4] = f2bf(a1.x); oo[5] = f2bf(a1.y); oo[6] = f2bf(a1.z); oo[7] = f2bf(a1.w);
                *(us8*)(As + (size_t)c * 8) = oo;
            } else {
                __builtin_amdgcn_global_load_lds(
                    (const __attribute__((address_space(1))) unsigned int*)((const unsigned short*)sg.A + (size_t)ga * lda + srck),
                    (__attribute__((address_space(3))) unsigned int*)(As + (size_t)c * 8), 16, 0, 0);
            }
            __builtin_amdgcn_global_load_lds(
                (const __attribute__((address_space(1))) unsigned int*)(Bt + (size_t)(bn + row) * K + srck),
                (__attribute__((address_space(3))) unsigned int*)(Bs + (size_t)c * 8), 16, 0, 0);
        }
        __syncthreads();
        #pragma unroll
        for (int kk = 0; kk < 2; ++kk) {
            bf16x8 af[4], bfr[4];
            #pragma unroll
            for (int m = 0; m < 4; ++m) {
                int row = wr + m * 16 + frow;
                int kc = kk * 4 + fkc;
                af[m] = *(const bf16x8*)(As + (size_t)((row << 3) + (kc ^ (row & 7))) * 8);
            }
            #pragma unroll
            for (int n = 0; n < 4; ++n) {
                int row = wc + n * 16 + frow;
                int kc = kk * 4 + fkc;
                bfr[n] = *(const bf16x8*)(Bs + (size_t)((row << 3) + (kc ^ (row & 7))) * 8);
            }
            #pragma unroll
            for (int m = 0; m < 4; ++m)
                #pragma unroll
                for (int n = 0; n < 4; ++n)
                    acc[m][n] = __builtin_amdgcn_mfma_f32_16x16x32_bf16(bfr[n], af[m], acc[m][n], 0, 0, 0);
        }
        __syncthreads();
    }

    // D = Bt_tile · A_tile^T: X-dim (lane>>4, reg) = C col, Y-dim (lane&15) = C row
    const int ccol0 = (lane >> 4) << 2;
    #pragma unroll
    for (int m = 0; m < 4; ++m) {
        int row = bm + wr + m * 16 + frow;
        if (row < M) {
            #pragma unroll
            for (int n = 0; n < 4; ++n) {
                int col = bn + wc + n * 16 + ccol0;
                f32x4 v = acc[m][n];
                if (bias) {
                    v[0] += bias[col + 0];
                    v[1] += bias[col + 1];
                    v[2] += bias[col + 2];
                    v[3] += bias[col + 3];
                }
                if constexpr (OBF) {
                    ushort4 oo;
                    oo.x = f2bf(v[0]); oo.y = f2bf(v[1]); oo.z = f2bf(v[2]); oo.w = f2bf(v[3]);
                    *(ushort4*)((unsigned short*)sg.C + (size_t)row * ldc + col) = oo;
                } else {
                    *(float4*)((float*)sg.C + (size_t)row * ldc + col) = make_float4(v[0], v[1], v[2], v[3]);
                }
            }
        }
    }
}

// ---------------- wave-per-node CSR mean-aggregate (bf16 RMW), 4-deep MLP ----------------
__global__ __launch_bounds__(256) void k_aggw(const int* __restrict__ offs,
                                              const int* __restrict__ csr,
                                              const unsigned short* __restrict__ proj, int ldp,
                                              const float* __restrict__ bias,
                                              unsigned short* __restrict__ outx, int ldo,
                                              int ndst) {
    int node = blockIdx.x * 4 + (threadIdx.x >> 6);
    int lane = threadIdx.x & 63;
    if (node >= ndst) return;
    int beg = offs[node], end = offs[node + 1];
    float s0 = 0.f, s1 = 0.f, s2 = 0.f, s3 = 0.f;
    const unsigned short* base = proj + lane * 4;
    int e = beg;
    for (; e + 3 < end; e += 4) {
        int i0 = csr[e], i1 = csr[e + 1], i2 = csr[e + 2], i3 = csr[e + 3];
        ushort4 u0 = *(const ushort4*)(base + (size_t)i0 * ldp);
        ushort4 u1 = *(const ushort4*)(base + (size_t)i1 * ldp);
        ushort4 u2 = *(const ushort4*)(base + (size_t)i2 * ldp);
        ushort4 u3 = *(const ushort4*)(base + (size_t)i3 * ldp);
        s0 += bf2f(u0.x) + bf2f(u1.x) + bf2f(u2.x) + bf2f(u3.x);
        s1 += bf2f(u0.y) + bf2f(u1.y) + bf2f(u2.y) + bf2f(u3.y);
        s2 += bf2f(u0.z) + bf2f(u1.z) + bf2f(u2.z) + bf2f(u3.z);
        s3 += bf2f(u0.w) + bf2f(u1.w) + bf2f(u2.w) + bf2f(u3.w);
    }
    for (; e < end; ++e) {
        ushort4 u = *(const ushort4*)(base + (size_t)csr[e] * ldp);
        s0 += bf2f(u.x); s1 += bf2f(u.y); s2 += bf2f(u.z); s3 += bf2f(u.w);
    }
    float inv = 1.f / fmaxf((float)(end - beg), 1.f);
    float4 b4 = ((const float4*)bias)[lane];
    size_t o = (size_t)node * ldo + lane * 4;
    ushort4 cur = *(const ushort4*)(outx + o);
    ushort4 w;
    w.x = f2bf(bf2f(cur.x) + s0 * inv + b4.x);
    w.y = f2bf(bf2f(cur.y) + s1 * inv + b4.y);
    w.z = f2bf(bf2f(cur.z) + s2 * inv + b4.z);
    w.w = f2bf(bf2f(cur.w) + s3 * inv + b4.w);
    *(ushort4*)(outx + o) = w;
}

// dual-source wave aggregate (reaction dst: p2r + m2r in one pass), 4-deep MLP
__global__ __launch_bounds__(256) void k_agg2w(const int* __restrict__ offsA,
                                               const int* __restrict__ csrA,
                                               const unsigned short* __restrict__ projA, int ldpA,
                                               const float* __restrict__ biasA,
                                               const int* __restrict__ offsB,
                                               const int* __restrict__ csrB,
                                               const unsigned short* __restrict__ projB, int ldpB,
                                               const float* __restrict__ biasB,
                                               unsigned short* __restrict__ outx, int ldo,
                                               int ndst) {
    int node = blockIdx.x * 4 + (threadIdx.x >> 6);
    int lane = threadIdx.x & 63;
    if (node >= ndst) return;
    float a0 = 0.f, a1 = 0.f, a2 = 0.f, a3 = 0.f;
    int begA = offsA[node], endA = offsA[node + 1];
    const unsigned short* baseA = projA + lane * 4;
    int e = begA;
    for (; e + 3 < endA; e += 4) {
        int i0 = csrA[e], i1 = csrA[e + 1], i2 = csrA[e + 2], i3 = csrA[e + 3];
        ushort4 u0 = *(const ushort4*)(baseA + (size_t)i0 * ldpA);
        ushort4 u1 = *(const ushort4*)(baseA + (size_t)i1 * ldpA);
        ushort4 u2 = *(const ushort4*)(baseA + (size_t)i2 * ldpA);
        ushort4 u3 = *(const ushort4*)(baseA + (size_t)i3 * ldpA);
        a0 += bf2f(u0.x) + bf2f(u1.x) + bf2f(u2.x) + bf2f(u3.x);
        a1 += bf2f(u0.y) + bf2f(u1.y) + bf2f(u2.y) + bf2f(u3.y);
        a2 += bf2f(u0.z) + bf2f(u1.z) + bf2f(u2.z) + bf2f(u3.z);
        a3 += bf2f(u0.w) + bf2f(u1.w) + bf2f(u2.w) + bf2f(u3.w);
    }
    for (; e < endA; ++e) {
        ushort4 u = *(const ushort4*)(baseA + (size_t)csrA[e] * ldpA);
        a0 += bf2f(u.x); a1 += bf2f(u.y); a2 += bf2f(u.z); a3 += bf2f(u.w);
    }
    float b0 = 0.f, b1 = 0.f, b2 = 0.f, b3 = 0.f;
    int begB = offsB[node], endB = offsB[node + 1];
    const unsigned short* baseB = projB + lane * 4;
    e = begB;
    for (; e + 3 < endB; e += 4) {
        int i0 = csrB[e], i1 = csrB[e + 1], i2 = csrB[e + 2], i3 = csrB[e + 3];
        ushort4 u0 = *(const ushort4*)(baseB + (size_t)i0 * ldpB);
        ushort4 u1 = *(const ushort4*)(baseB + (size_t)i1 * ldpB);
        ushort4 u2 = *(const ushort4*)(baseB + (size_t)i2 * ldpB);
        ushort4 u3 = *(const ushort4*)(baseB + (size_t)i3 * ldpB);
        b0 += bf2f(u0.x) + bf2f(u1.x) + bf2f(u2.x) + bf2f(u3.x);
        b1 += bf2f(u0.y) + bf2f(u1.y) + bf2f(u2.y) + bf2f(u3.y);
        b2 += bf2f(u0.z) + bf2f(u1.z) + bf2f(u2.z) + bf2f(u3.z);
        b3 += bf2f(u0.w) + bf2f(u1.w) + bf2f(u2.w) + bf2f(u3.w);
    }
    for (; e < endB; ++e) {
        ushort4 u = *(const ushort4*)(baseB + (size_t)csrB[e] * ldpB);
        b0 += bf2f(u.x); b1 += bf2f(u.y); b2 += bf2f(u.z); b3 += bf2f(u.w);
    }
    float invA = 1.f / fmaxf((float)(endA - begA), 1.f);
    float invB = 1.f / fmaxf((float)(endB - begB), 1.f);
    float4 bA = ((const float4*)biasA)[lane];
    float4 bB = ((const float4*)biasB)[lane];
    size_t o = (size_t)node * ldo + lane * 4;
    ushort4 cur = *(const ushort4*)(outx + o);
    ushort4 w;
    w.x = f2bf(bf2f(cur.x) + a0 * invA + bA.x + b0 * invB + bB.x);
    w.y = f2bf(bf2f(cur.y) + a1 * invA + bA.y + b1 * invB + bB.y);
    w.z = f2bf(bf2f(cur.z) + a2 * invA + bA.z + b2 * invB + bB.z);
    w.w = f2bf(bf2f(cur.w) + a3 * invA + bA.w + b3 * invB + bB.w);
    *(ushort4*)(outx + o) = w;
}

// ---------------- cosine: one wave per row ----------------
__global__ __launch_bounds__(256) void k_cos(const float* __restrict__ ro,
                                             const float* __restrict__ pr,
                                             const int* __restrict__ types,
                                             float* __restrict__ out, int nr) {
    int row = blockIdx.x * 4 + (threadIdx.x >> 6);
    int lane = threadIdx.x & 63;
    if (row >= nr) return;
    int t = types[row];
    float2 r = ((const float2*)(ro + (size_t)row * OUTD_))[lane];
    float2 nn = ((const float2*)(pr + (size_t)row * 384 + t * OUTD_))[lane];
    float num = r.x * nn.x + r.y * nn.y;
    float d1 = r.x * r.x + r.y * r.y;
    float d2 = nn.x * nn.x + nn.y * nn.y;
    #pragma unroll
    for (int s = 1; s < 64; s <<= 1) {
        num += __shfl_xor(num, s);
        d1 += __shfl_xor(d1, s);
        d2 += __shfl_xor(d2, s);
    }
    if (lane == 0) out[row] = (num / fmaxf(sqrtf(d1) * sqrtf(d2), 1e-8f) + 1.f) * 0.5f;
}

extern "C" void kernel_launch(void* const* d_in, const int* in_sizes, int n_in,
                              void* d_out, int out_size, void* d_ws, size_t ws_size,
                              hipStream_t stream) {
    const float* x_r0 = (const float*)d_in[0];
    const float* x_p0 = (const float*)d_in[1];
    const float* x_m0 = (const float*)d_in[2];
    const int* e_src[4] = {(const int*)d_in[3], (const int*)d_in[5], (const int*)d_in[7], (const int*)d_in[9]};
    const int* e_dst[4] = {(const int*)d_in[4], (const int*)d_in[6], (const int*)d_in[8], (const int*)d_in[10]};
    const float* notes = (const float*)d_in[11];
    const int* types = (const int*)d_in[12];
    const float* Wl0 = (const float*)d_in[13];
    const float* Wr0 = (const float*)d_in[14];
    const float* bl0 = (const float*)d_in[15];
    const float* WlL = (const float*)d_in[16];
    const float* WrL = (const float*)d_in[17];
    const float* blL = (const float*)d_in[18];
    const float* Wre = (const float*)d_in[19];
    const float* bre = (const float*)d_in[20];
    const float* Wn  = (const float*)d_in[21];
    const float* bn  = (const float*)d_in[22];
    float* out = (float*)d_out;

    // ---- workspace carve ----
    uintptr_t base = (uintptr_t)d_ws;
    auto alloc = [&](size_t bytes) -> void* {
        uintptr_t p = (base + 255) & ~(uintptr_t)255;
        base = p + bytes;
        return (void*)p;
    };
    unsigned short* Rb[2] = {(unsigned short*)alloc((size_t)NR_ * 768 * 2),
                             (unsigned short*)alloc((size_t)NR_ * 768 * 2)};
    unsigned short* Pb[2] = {(unsigned short*)alloc((size_t)NP2_ * 512 * 2),
                             (unsigned short*)alloc((size_t)NP2_ * 512 * 2)};
    unsigned short* Mb[2] = {(unsigned short*)alloc((size_t)NM_ * 512 * 2),
                             (unsigned short*)alloc((size_t)NM_ * 512 * 2)};
    float* ro = (float*)alloc((size_t)NR_ * OUTD_ * 4);
    float* pr = (float*)alloc((size_t)NR_ * 384 * 4);
    unsigned short* wbf = (unsigned short*)alloc((size_t)4000000 * 2);
    int* csum = (int*)alloc(160 * 4);
    int nd[4] = {NR_, NR_, NP2_, NM_};
    Csr4 cs{};
    for (int t = 0; t < 4; ++t) {
        cs.src[t] = e_src[t]; cs.dst[t] = e_dst[t]; cs.n[t] = nd[t];
        cs.offs[t] = (int*)alloc(((size_t)nd[t] + 1) * 4);
        cs.cur[t]  = (int*)alloc((size_t)nd[t] * 4);
        cs.csr[t]  = (int*)alloc((size_t)NE_ * 4);
    }

    // ---- weight transpose+convert: concatenated B blocks, bf16 [N][K] ----
    unsigned short *BR[4], *BP[4], *BM[4], *Bre, *Bn;
    {
        WBatch wb{};
        int cnt = 0;
        size_t woff = 0;
        auto add = [&](const float* a, const float* bb, int K, int N) -> unsigned short* {
            unsigned short* dst = wbf + woff;
            woff += (size_t)K * N;
            wb.it[cnt] = WItem{a, bb, dst, K, N};
            ++cnt;
            return dst;
        };
        const size_t w0 = (size_t)EMB_ * HID_;
        const size_t wl = (size_t)HID_ * HID_;
        for (int l = 0; l < 4; ++l) {
            int K = (l == 0) ? EMB_ : HID_;
            const float* Wr_ = (l == 0) ? Wr0 : WrL + (size_t)(l - 1) * 4 * wl;
            const float* Wl_ = (l == 0) ? Wl0 : WlL + (size_t)(l - 1) * 4 * wl;
            size_t ws_ = (l == 0) ? w0 : wl;
            BR[l] = add(Wr_ + 0 * ws_, Wr_ + 1 * ws_, K, HID_);  // WrC
            add(Wl_ + 2 * ws_, nullptr, K, HID_);                 // Wl2 (r2p proj)
            add(Wl_ + 3 * ws_, nullptr, K, HID_);                 // Wl3 (r2m proj)
            BP[l] = add(Wr_ + 2 * ws_, nullptr, K, HID_);         // Wr2
            add(Wl_ + 0 * ws_, nullptr, K, HID_);                 // Wl0 (p2r proj)
            BM[l] = add(Wr_ + 3 * ws_, nullptr, K, HID_);         // Wr3
            add(Wl_ + 1 * ws_, nullptr, K, HID_);                 // Wl1 (m2r proj)
        }
        Bre = add(Wre, nullptr, HID_, OUTD_);
        Bn = add(Wn + 0 * (size_t)EMB_ * OUTD_, nullptr, EMB_, OUTD_);
        add(Wn + 1 * (size_t)EMB_ * OUTD_, nullptr, EMB_, OUTD_);
        add(Wn + 2 * (size_t)EMB_ * OUTD_, nullptr, EMB_, OUTD_);
        k_wconvT<<<dim3(128, cnt), 256, 0, stream>>>(wb);
    }

    // ---- CSR build (batched over the 4 edge types) ----
    k_zero4<<<dim3((NP2_ + 255) / 256, 4), 256, 0, stream>>>(cs);
    k_deg4<<<dim3((NE_ + 255) / 256, 4), 256, 0, stream>>>(cs);
    k_scanA<<<dim3(40, 4), 256, 0, stream>>>(cs, csum);
    k_scanB<<<1, 64, 0, stream>>>(cs, csum);
    k_scanC<<<dim3((NP2_ + 255) / 256, 4), 256, 0, stream>>>(cs, csum);
    k_scatter4<<<dim3((NE_ + 255) / 256, 4), 256, 0, stream>>>(cs);

    // ---- batched GEMM helper ----
    const int MT_R = (NR_ + 127) / 128;    // 128
    const int MT_P = (NP2_ + 127) / 128;   // 313
    const int MT_M = (NM_ + 127) / 128;    // 235
    auto seg = [](const void* A, const unsigned short* Bt, void* C, const float* bias,
                  int lda, int ldc, int M, int K, int ntn, int blk0) -> GSeg {
        return GSeg{A, Bt, C, bias, lda, ldc, M, K, ntn, blk0};
    };

    for (int l = 0; l < 4; ++l) {
        int K = (l == 0) ? EMB_ : HID_;
        unsigned short* R = Rb[l & 1];
        unsigned short* P = Pb[l & 1];
        unsigned short* M = Mb[l & 1];
        const float* bl_ = (l == 0) ? bl0 : blL + (size_t)(l - 1) * 4 * HID_;

        GBatch gb{};
        int nR = MT_R * 6, nP = MT_P * 4, nM = MT_M * 4;
        if (l == 0) {
            gb.s[0] = seg(x_r0, BR[0], R, nullptr, EMB_, 768, NR_, EMB_, 6, 0);
            gb.s[1] = seg(x_p0, BP[0], P, nullptr, EMB_, 512, NP2_, EMB_, 4, nR);
            gb.s[2] = seg(x_m0, BM[0], M, nullptr, EMB_, 512, NM_, EMB_, 4, nR + nP);
        } else {
            gb.s[0] = seg(Rb[(l - 1) & 1], BR[l], R, nullptr, 768, 768, NR_, K, 6, 0);
            gb.s[1] = seg(Pb[(l - 1) & 1], BP[l], P, nullptr, 512, 512, NP2_, K, 4, nR);
            gb.s[2] = seg(Mb[(l - 1) & 1], BM[l], M, nullptr, 512, 512, NM_, K, 4, nR + nP);
        }
        gb.b1 = nR; gb.b2 = nR + nP; gb.tot = nR + nP + nM;
        if (l == 0) k_gemmb<true, true><<<gb.tot, 256, 0, stream>>>(gb);
        else        k_gemmb<true, false><<<gb.tot, 256, 0, stream>>>(gb);

        // reaction <- mean(projP) + mean(projM); protein <- mean(projR); molecule <- mean(projR2)
        k_agg2w<<<(NR_ + 3) / 4, 256, 0, stream>>>(cs.offs[0], cs.csr[0], P + 256, 512, bl_ + 0 * HID_,
                                                   cs.offs[1], cs.csr[1], M + 256, 512, bl_ + 1 * HID_,
                                                   R, 768, NR_);
        k_aggw<<<(NP2_ + 3) / 4, 256, 0, stream>>>(cs.offs[2], cs.csr[2], R + 256, 768, bl_ + 2 * HID_, P, 512, NP2_);
        k_aggw<<<(NM_ + 3) / 4, 256, 0, stream>>>(cs.offs[3], cs.csr[3], R + 512, 768, bl_ + 3 * HID_, M, 512, NM_);
    }

    // ---- final: reaction proj (f32 out) + 3 node projs (f32 out, concatenated) + cosine ----
    {
        GBatch g1{};
        g1.s[0] = seg(Rb[1], Bre, ro, bre, 768, OUTD_, NR_, HID_, 1, 0);
        g1.b1 = g1.b2 = g1.tot = MT_R * 1;
        k_gemmb<false, false><<<g1.tot, 256, 0, stream>>>(g1);
        GBatch g2{};
        g2.s[0] = seg(notes, Bn, pr, bn, EMB_, 384, NR_, EMB_, 3, 0);
        g2.b1 = g2.b2 = g2.tot = MT_R * 3;
        k_gemmb<false, true><<<g2.tot, 256, 0, stream>>>(g2);
    }
    k_cos<<<NR_ / 4, 256, 0, stream>>>(ro, pr, types, out, NR_);
}